// Round 7
// baseline (93.999 us; speedup 1.0000x reference)
//
#include <hip/hip_runtime.h>

#define IMG_H 512
#define IMG_W 512
#define NB    32
#define HW    (IMG_H * IMG_W)
#define SEGS  32             // 16-px segments per row
#define RPB   8              // rows per block (256 threads / 32 segs)
#define GX    (IMG_H / RPB)  // 64 blocks in x
#define NPART GX             // partials per batch
#define NBLK  (GX * NB)      // total blocks = 2048

// Packed class masks for 16 px: bits 0..15 = (y==1), bits 16..31 = (y==2).
// y in {0,1,2}  =>  (y==1) == (y&1), (y==2) == (y>>1). No compares needed.
__device__ __forceinline__ unsigned build16(const int* __restrict__ row) {
    unsigned m = 0u;
    #pragma unroll
    for (int q = 0; q < 4; ++q) {
        const int4 w = *reinterpret_cast<const int4*>(row + 4 * q);
        const unsigned b1 = (unsigned)(w.x & 1)        | ((unsigned)(w.y & 1) << 1)
                          | ((unsigned)(w.z & 1) << 2) | ((unsigned)(w.w & 1) << 3);
        const unsigned b2 = (unsigned)(w.x >> 1)        | ((unsigned)(w.y >> 1) << 1)
                          | ((unsigned)(w.z >> 1) << 2) | ((unsigned)(w.w >> 1) << 3);
        m |= (b1 << (4 * q)) | (b2 << (16 + 4 * q));
    }
    return m;
}

// Each thread: one 16-pixel row segment. Wave = 2 adjacent rows x 32 segs.
// Own + outward row masks built locally; third row via shfl(lane^32).
// Last finished block reduces the 2048 partials and writes the scalar output.
__global__ __launch_bounds__(256) void iou_kernel(const float* __restrict__ yhat,
                                                  const int* __restrict__ y,
                                                  unsigned long long* __restrict__ part,
                                                  unsigned long long* __restrict__ ctr,
                                                  float* __restrict__ out) {
    const int b   = blockIdx.y;
    const int t   = blockIdx.x * 256 + threadIdx.x;
    const int h   = t >> 5;                 // row
    const int seg = t & 31;
    const int wbase = seg << 4;             // *16

    const int lane     = threadIdx.x & 63;
    const bool lowHalf = (lane < 32);       // lanes 0-31: row h pairs with h+1 below

    // ---- Issue y loads first (consumed first), then the yhat stream ----
    const int* yb = y + (size_t)b * HW;
    const int ho  = lowHalf ? (h - 1) : (h + 1);            // outward row
    const bool ov = (unsigned)ho < IMG_H;
    const int hoc = ov ? ho : h;

    const unsigned mOwn = build16(yb + (size_t)h   * IMG_W + wbase);
    const unsigned mOut = build16(yb + (size_t)hoc * IMG_W + wbase);

    const float* yh = yhat + (size_t)b * 3 * HW + (size_t)h * IMG_W + wbase;
    const float4 qa0 = *reinterpret_cast<const float4*>(yh);
    const float4 qa1 = *reinterpret_cast<const float4*>(yh + 4);
    const float4 qa2 = *reinterpret_cast<const float4*>(yh + 8);
    const float4 qa3 = *reinterpret_cast<const float4*>(yh + 12);
    const float4 qb0 = *reinterpret_cast<const float4*>(yh + HW);
    const float4 qb1 = *reinterpret_cast<const float4*>(yh + HW + 4);
    const float4 qb2 = *reinterpret_cast<const float4*>(yh + HW + 8);
    const float4 qb3 = *reinterpret_cast<const float4*>(yh + HW + 12);
    const float4 qc0 = *reinterpret_cast<const float4*>(yh + 2 * HW);
    const float4 qc1 = *reinterpret_cast<const float4*>(yh + 2 * HW + 4);
    const float4 qc2 = *reinterpret_cast<const float4*>(yh + 2 * HW + 8);
    const float4 qc3 = *reinterpret_cast<const float4*>(yh + 2 * HW + 12);

    // ---- Assemble 3 rows via partner shuffle; L/R halo shuffles ----
    const unsigned mPar = __shfl(mOwn, lane ^ 32, 64);      // partner row
    const unsigned mT = lowHalf ? mOut : mPar;
    const unsigned mB = lowHalf ? mPar : mOut;
    const bool vT = lowHalf ? ov : true;
    const bool vB = lowHalf ? true : ov;

    const int laneL = (lane + 63) & 63;   // cross-half leakage only at seg borders (masked)
    const int laneR = (lane + 1) & 63;
    const unsigned tL = __shfl(mT, laneL, 64),   tR = __shfl(mT, laneR, 64);
    const unsigned cL = __shfl(mOwn, laneL, 64), cR = __shfl(mOwn, laneR, 64);
    const unsigned bL = __shfl(mB, laneL, 64),   bR = __shfl(mB, laneR, 64);

    // ext bit j = column wbase-1+j (j=0..17)
    #define EXT1(m, ml, mr) ((((m) & 0xFFFFu) << 1) | (((ml) >> 15) & 1u) | (((mr) & 1u) << 17))
    #define EXT2(m, ml, mr) ((((m) >> 16) << 1)     | ((ml) >> 31)        | ((((mr) >> 16) & 1u) << 17))
    const unsigned eT1 = EXT1(mT, tL, tR),   eT2 = EXT2(mT, tL, tR);
    const unsigned eC1 = EXT1(mOwn, cL, cR), eC2 = EXT2(mOwn, cL, cR);
    const unsigned eB1 = EXT1(mB, bL, bR),   eB2 = EXT2(mB, bL, bR);

    const unsigned ALL = 0x3FFFFu;
    unsigned vmask = ALL;
    if (seg == 0)        vmask &= ~1u;
    if (seg == SEGS - 1) vmask &= ~(1u << 17);
    const unsigned inv = ALL & ~vmask;

    unsigned and1 = eC1 & (vT ? eT1 : ALL) & (vB ? eB1 : ALL);
    unsigned and2 = eC2 & (vT ? eT2 : ALL) & (vB ? eB2 : ALL);
    unsigned or1  = eC1 | (vT ? eT1 : 0u)  | (vB ? eB1 : 0u);
    unsigned or2  = eC2 | (vT ? eT2 : 0u)  | (vB ? eB2 : 0u);
    and1 |= inv;   and2 |= inv;
    or1  &= vmask; or2  &= vmask;

    const unsigned E1 = and1 & (and1 >> 1) & (and1 >> 2);
    const unsigned E2 = and2 & (and2 >> 1) & (and2 >> 2);
    const unsigned D1 = or1  | (or1  >> 1) | (or1  >> 2);
    const unsigned D2 = or2  | (or2  >> 1) | (or2  >> 2);

    // ---- Argmax -> class bitmasks (strict-> first-occurrence tie-break) ----
    const float A[16]  = {qa0.x,qa0.y,qa0.z,qa0.w, qa1.x,qa1.y,qa1.z,qa1.w,
                          qa2.x,qa2.y,qa2.z,qa2.w, qa3.x,qa3.y,qa3.z,qa3.w};
    const float Bv[16] = {qb0.x,qb0.y,qb0.z,qb0.w, qb1.x,qb1.y,qb1.z,qb1.w,
                          qb2.x,qb2.y,qb2.z,qb2.w, qb3.x,qb3.y,qb3.z,qb3.w};
    const float Cv[16] = {qc0.x,qc0.y,qc0.z,qc0.w, qc1.x,qc1.y,qc1.z,qc1.w,
                          qc2.x,qc2.y,qc2.z,qc2.w, qc3.x,qc3.y,qc3.z,qc3.w};
    unsigned P1 = 0u, P2 = 0u;
    #pragma unroll
    for (int j = 0; j < 16; ++j) {
        const bool bgt = Bv[j] > A[j];
        const bool c2  = Cv[j] > fmaxf(A[j], Bv[j]);   // p==2 iff C strictly beats both
        const bool c1  = bgt && !c2;                   // p==1 iff B>A and C doesn't win
        P1 |= (c1 ? 1u : 0u) << j;
        P2 |= (c2 ? 1u : 0u) << j;
    }

    const unsigned inter = (unsigned)__popc((D2 & P2) | (D1 & ~D2 & P1));
    const unsigned uni   = (unsigned)__popc((E1 | E2 | P1 | P2) & 0xFFFFu);

    // ---- Reduce: wave -> block -> one partial store per block ----
    unsigned long long packed = (unsigned long long)inter | ((unsigned long long)uni << 32);
    #pragma unroll
    for (int off = 32; off > 0; off >>= 1)
        packed += __shfl_down(packed, off, 64);

    __shared__ unsigned long long wsum[4];
    __shared__ int amLast;
    const int wave = threadIdx.x >> 6;
    if ((threadIdx.x & 63) == 0) wsum[wave] = packed;
    __syncthreads();
    if (threadIdx.x == 0) {
        part[(size_t)b * NPART + blockIdx.x] = wsum[0] + wsum[1] + wsum[2] + wsum[3];
        __threadfence();                                  // partial visible before count
        const unsigned long long old = atomicAdd(ctr, 1ull);
        amLast = (old == (unsigned long long)(NBLK - 1)) ? 1 : 0;
    }
    __syncthreads();

    // ---- Last block: reduce all 2048 partials, write the scalar ----
    if (amLast) {
        __threadfence();                                  // see all partials
        const int tt = threadIdx.x;
        const int bb = tt >> 3;
        const int k  = tt & 7;
        unsigned long long s = 0ull;
        #pragma unroll
        for (int i = 0; i < 8; ++i)
            s += part[(size_t)bb * NPART + k * 8 + i];
        s += __shfl_down(s, 4, 8);
        s += __shfl_down(s, 2, 8);
        s += __shfl_down(s, 1, 8);

        __shared__ float r[NB];
        if (k == 0) {
            const float fi = (float)(unsigned int)(s & 0xFFFFFFFFull);
            const float fu = (float)(unsigned int)(s >> 32);
            r[bb] = fi / fu;
        }
        __syncthreads();
        if (tt < 32) {
            float v = r[tt];
            #pragma unroll
            for (int off = 16; off > 0; off >>= 1)
                v += __shfl_down(v, off, 32);
            if (tt == 0) out[0] = v / (float)NB;
        }
    }
}

extern "C" void kernel_launch(void* const* d_in, const int* in_sizes, int n_in,
                              void* d_out, int out_size, void* d_ws, size_t ws_size,
                              hipStream_t stream) {
    const float* yhat = (const float*)d_in[0];
    const int*   y    = (const int*)d_in[1];
    float*       out  = (float*)d_out;
    unsigned long long* ctr  = (unsigned long long*)d_ws;        // [0]: done counter
    unsigned long long* part = (unsigned long long*)d_ws + 16;   // 128B offset: 2048 partials

    hipMemsetAsync(d_ws, 0, sizeof(unsigned long long), stream); // reset counter each call

    dim3 grid(GX, NB, 1);
    iou_kernel<<<grid, 256, 0, stream>>>(yhat, y, part, ctr, out);
}

// Round 8
// 33.137 us; speedup vs baseline: 2.8367x; 2.8367x over previous
//
#include <hip/hip_runtime.h>

#define IMG_H 512
#define IMG_W 512
#define NB    32
#define HW    (IMG_H * IMG_W)
#define NPART 256            // blocks per image (2 rows per block)

// Pack 4 px of y (values in {0,1,2}) into mask byte: bits0-3 = (y==1), bits4-7 = (y==2).
__device__ __forceinline__ unsigned packmask(const int4 w) {
    const unsigned m1 = (unsigned)(w.x & 1)        | ((unsigned)(w.y & 1) << 1)
                      | ((unsigned)(w.z & 1) << 2) | ((unsigned)(w.w & 1) << 3);
    const unsigned m2 = (unsigned)(w.x >> 1)        | ((unsigned)(w.y >> 1) << 1)
                      | ((unsigned)(w.z >> 1) << 2) | ((unsigned)(w.w >> 1) << 3);
    return m1 | (m2 << 4);
}

// Block = 2 full rows (1024 px). Thread = 4 consecutive px -> every vector load is
// 64 lanes x 16B consecutive (minimum line-lookups per instruction).
__global__ __launch_bounds__(256) void iou_kernel(const float* __restrict__ yhat,
                                                  const int* __restrict__ y,
                                                  unsigned* __restrict__ part) {
    const int b    = blockIdx.y;
    const int row0 = blockIdx.x << 1;          // first of the block's 2 rows
    const int rs   = threadIdx.x >> 7;         // 0: row0, 1: row0+1
    const int c4   = threadIdx.x & 127;        // which float4/int4 within the row
    const int h    = row0 + rs;

    // ---- Dominant yhat stream first (independent of LDS phase) ----
    const float* yh = yhat + (size_t)b * 3 * HW + (size_t)h * IMG_W + (c4 << 2);
    const float4 va = *reinterpret_cast<const float4*>(yh);
    const float4 vb = *reinterpret_cast<const float4*>(yh + HW);
    const float4 vc = *reinterpret_cast<const float4*>(yh + 2 * HW);

    // ---- y: own row + outward row (clamped; validity applied later) ----
    const int* yb = y + (size_t)b * HW;
    const int ho  = rs ? (h + 1) : (h - 1);
    const int hoc = min(max(ho, 0), IMG_H - 1);
    const int4 wOwn = *reinterpret_cast<const int4*>(yb + (size_t)h   * IMG_W + (c4 << 2));
    const int4 wOut = *reinterpret_cast<const int4*>(yb + (size_t)hoc * IMG_W + (c4 << 2));

    // ---- Mask exchange via LDS: slot s holds row row0-1+s ----
    __shared__ unsigned M[4][128];             // 2 KB
    M[rs + 1][c4]      = packmask(wOwn);       // own rows -> slots 1,2
    M[rs ? 3 : 0][c4]  = packmask(wOut);       // outward rows -> slots 3,0
    __syncthreads();

    // ---- 3x3 erode/dilate from LDS masks ----
    // ext bit j = column c4*4-1+j (j=0..5). AND identity 1, OR identity 0.
    const int cl = (c4 > 0)   ? c4 - 1 : 0;
    const int cr = (c4 < 127) ? c4 + 1 : 127;

    unsigned vmask = 0x3Fu;
    if (c4 == 0)   vmask &= ~1u;               // image-left border
    if (c4 == 127) vmask &= ~(1u << 5);        // image-right border
    const unsigned inv = 0x3Fu & ~vmask;

    unsigned and1 = 0x3Fu, or1 = 0u, and2 = 0x3Fu, or2 = 0u;
    #pragma unroll
    for (int dr = 0; dr < 3; ++dr) {
        const int s = rs + dr;                 // slot; row = row0-1+s
        const bool valid = (s == 0) ? (row0 > 0)
                         : (s == 3) ? (row0 + 2 < IMG_H)
                         : true;
        const unsigned L = M[s][cl];
        const unsigned C = M[s][c4];
        const unsigned R = M[s][cr];
        const unsigned e1 = ((L >> 3) & 1u) | ((C & 0xFu) << 1) | ((R & 1u) << 5);
        const unsigned e2 = ((L >> 7) & 1u) | (((C >> 4) & 0xFu) << 1) | (((R >> 4) & 1u) << 5);
        and1 &= valid ? e1 : 0x3Fu;
        and2 &= valid ? e2 : 0x3Fu;
        or1  |= valid ? e1 : 0u;
        or2  |= valid ? e2 : 0u;
    }
    and1 |= inv;   and2 |= inv;
    or1  &= vmask; or2  &= vmask;

    // pixel p (0..3) <- ext bits p, p+1, p+2
    const unsigned E1 = and1 & (and1 >> 1) & (and1 >> 2);
    const unsigned E2 = and2 & (and2 >> 1) & (and2 >> 2);
    const unsigned D1 = or1  | (or1  >> 1) | (or1  >> 2);
    const unsigned D2 = or2  | (or2  >> 1) | (or2  >> 2);

    // ---- Argmax over 3 channels -> 4-bit class masks ----
    const float A[4]  = {va.x, va.y, va.z, va.w};
    const float Bv[4] = {vb.x, vb.y, vb.z, vb.w};
    const float Cv[4] = {vc.x, vc.y, vc.z, vc.w};
    unsigned P1 = 0u, P2 = 0u;
    #pragma unroll
    for (int j = 0; j < 4; ++j) {
        int   p    = 0;
        float best = A[j];
        if (Bv[j] > best) { best = Bv[j]; p = 1; }
        if (Cv[j] > best) {               p = 2; }
        P1 |= ((p == 1) ? 1u : 0u) << j;
        P2 |= ((p == 2) ? 1u : 0u) << j;
    }

    const unsigned inter = (unsigned)__popc((D2 & P2) | (D1 & ~D2 & P1));
    const unsigned uni   = (unsigned)__popc((E1 | E2 | P1 | P2) & 0xFu);

    // ---- Reduce: wave -> block -> one u32 partial per block ----
    unsigned pk = inter | (uni << 16);         // block totals <= 1024 per field
    #pragma unroll
    for (int off = 32; off > 0; off >>= 1)
        pk += __shfl_down(pk, off, 64);

    __shared__ unsigned wsum[4];
    const int wave = threadIdx.x >> 6;
    if ((threadIdx.x & 63) == 0) wsum[wave] = pk;
    __syncthreads();
    if (threadIdx.x == 0)
        part[(size_t)b * NPART + blockIdx.x] = wsum[0] + wsum[1] + wsum[2] + wsum[3];
}

__global__ void finalize_kernel(const unsigned* __restrict__ part,
                                float* __restrict__ out) {
    // 256 threads: 8 threads per batch, each sums 32 of the 256 partials.
    const int t = threadIdx.x;
    const int b = t >> 3;
    const int k = t & 7;
    unsigned si = 0u, su = 0u;
    #pragma unroll
    for (int i = 0; i < 32; ++i) {
        const unsigned p = part[(size_t)b * NPART + k * 32 + i];
        si += p & 0xFFFFu;
        su += p >> 16;
    }
    si += __shfl_down(si, 4, 8);  su += __shfl_down(su, 4, 8);
    si += __shfl_down(si, 2, 8);  su += __shfl_down(su, 2, 8);
    si += __shfl_down(si, 1, 8);  su += __shfl_down(su, 1, 8);

    __shared__ float r[NB];
    if (k == 0)
        r[b] = (float)si / (float)su;
    __syncthreads();
    if (t < 32) {
        float v = r[t];
        #pragma unroll
        for (int off = 16; off > 0; off >>= 1)
            v += __shfl_down(v, off, 32);
        if (t == 0) out[0] = v / (float)NB;
    }
}

extern "C" void kernel_launch(void* const* d_in, const int* in_sizes, int n_in,
                              void* d_out, int out_size, void* d_ws, size_t ws_size,
                              hipStream_t stream) {
    const float* yhat = (const float*)d_in[0];
    const int*   y    = (const int*)d_in[1];
    float*       out  = (float*)d_out;
    unsigned*    part = (unsigned*)d_ws;       // 32*256 u32 = 32 KB, fully rewritten each call

    dim3 grid(NPART, NB, 1);
    iou_kernel<<<grid, 256, 0, stream>>>(yhat, y, part);
    finalize_kernel<<<1, 256, 0, stream>>>(part, out);
}